// Round 1
// baseline (2029.011 us; speedup 1.0000x reference)
//
#include <hip/hip_runtime.h>
#include <math.h>

#define HW 65536

// ---------- twiddle tables: cosT[k][x] = cos(2*pi*k*x/256), sinT likewise ----------
__global__ __launch_bounds__(256) void k_tables(float* __restrict__ cosT, float* __restrict__ sinT) {
  int idx = blockIdx.x * 256 + threadIdx.x;   // 4096 = 16 k * 256 x
  int k = idx >> 8, xx = idx & 255;
  int t = (k * xx) & 255;
  float ang = (float)t * 0.0245436926061702596f; // 2*pi/256
  cosT[idx] = cosf(ang);
  sinT[idx] = sinf(ang);
}

// ---------- fc0: (B,3,H,W) -> (B,64,H,W) ----------
__global__ __launch_bounds__(256) void k_fc0(const float* __restrict__ x, const float* __restrict__ w,
                                             const float* __restrict__ b, float* __restrict__ h) {
  int bid = blockIdx.x;                 // 1024 = B*H
  int bb = bid >> 8, y = bid & 255;
  int tx = threadIdx.x;
  __shared__ float ws[192];
  __shared__ float bs[64];
  if (tx < 192) ws[tx] = w[tx];
  if (tx < 64) bs[tx] = b[tx];
  __syncthreads();
  const float* xp = x + ((bb * 3) * 256 + y) * 256 + tx;
  float v0 = xp[0], v1 = xp[HW], v2 = xp[2 * HW];
  float* hp = h + ((bb * 64) * 256 + y) * 256 + tx;
#pragma unroll 4
  for (int o = 0; o < 64; ++o) {
    hp[o * HW] = bs[o] + ws[o * 3] * v0 + ws[o * 3 + 1] * v1 + ws[o * 3 + 2] * v2;
  }
}

// ---------- F1: row DFT. rows r=(b*64+c)*256+y ; A[r][k] = sum_x h[r][x] e^{-2pi i k x/256} ----------
__global__ __launch_bounds__(256) void k_f1(const float* __restrict__ h, const float4* __restrict__ cosT4,
                                            const float4* __restrict__ sinT4, float2* __restrict__ A) {
  int tid = threadIdx.x;
  int r = blockIdx.x * 16 + (tid >> 4);
  int k = tid & 15;
  const float4* row = (const float4*)(h + r * 256);
  const float4* cp = cosT4 + k * 64;
  const float4* sp = sinT4 + k * 64;
  float ar = 0.f, ai = 0.f;
#pragma unroll 4
  for (int i = 0; i < 64; ++i) {
    float4 v = row[i], c = cp[i], s = sp[i];
    ar += v.x * c.x + v.y * c.y + v.z * c.z + v.w * c.w;
    ai -= v.x * s.x + v.y * s.y + v.z * s.z + v.w * s.w;
  }
  A[r * 16 + k] = make_float2(ar, ai);
}

// ---------- F2: col DFT over y. X[plane][ky*16+kx] = sum_y e^{-2pi i ky y/256} A[plane,y,kx] ----------
__global__ __launch_bounds__(256) void k_f2(const float2* __restrict__ A, const float* __restrict__ cosT,
                                            const float* __restrict__ sinT, float2* __restrict__ X) {
  int plane = blockIdx.x;               // 256 = B*C
  int ky = threadIdx.x >> 4, kx = threadIdx.x & 15;
  const float2* Ap = A + plane * 256 * 16 + kx;
  float xr = 0.f, xi = 0.f;
#pragma unroll 4
  for (int y = 0; y < 256; ++y) {
    float2 a = Ap[y * 16];
    float c = cosT[ky * 256 + y], s = sinT[ky * 256 + y];
    xr += c * a.x + s * a.y;
    xi += c * a.y - s * a.x;
  }
  X[plane * 256 + ky * 16 + kx] = make_float2(xr, xi);
}

// ---------- MIX: Y[b,o,m] = sum_c X[b,c,m] * (wr+i wi)[c,o,m] ----------
__global__ __launch_bounds__(256) void k_mix(const float2* __restrict__ X, const float* __restrict__ wr,
                                             const float* __restrict__ wi, float2* __restrict__ Y) {
  int o = blockIdx.x >> 2;              // 256 blocks = 64 o * 4 mode-chunks
  int mc = blockIdx.x & 3;
  int b = threadIdx.x >> 6;
  int m = mc * 64 + (threadIdx.x & 63);
  float yr = 0.f, yi = 0.f;
#pragma unroll 4
  for (int c = 0; c < 64; ++c) {
    float2 xv = X[(b * 64 + c) * 256 + m];
    float r = wr[(c * 64 + o) * 256 + m];
    float im = wi[(c * 64 + o) * 256 + m];
    yr += xv.x * r - xv.y * im;
    yi += xv.x * im + xv.y * r;
  }
  Y[(b * 64 + o) * 256 + m] = make_float2(yr, yi);
}

// ---------- INV1: g[b,o,y,kx] = sum_ky Y[b,o,ky,kx] e^{+2pi i ky y/256}, scaled ----------
__global__ __launch_bounds__(256) void k_inv1(const float2* __restrict__ Y, const float* __restrict__ cosT,
                                              const float* __restrict__ sinT, float2* __restrict__ g) {
  int plane = blockIdx.x;               // 256 = B*O
  int y = threadIdx.x;
  __shared__ float2 Ys[256];
  Ys[threadIdx.x] = Y[plane * 256 + threadIdx.x];
  __syncthreads();
  float gr[16], gi[16];
#pragma unroll
  for (int k = 0; k < 16; ++k) { gr[k] = 0.f; gi[k] = 0.f; }
  for (int ky = 0; ky < 16; ++ky) {
    float c = cosT[ky * 256 + y], s = sinT[ky * 256 + y];
#pragma unroll
    for (int kx = 0; kx < 16; ++kx) {
      float2 v = Ys[ky * 16 + kx];
      gr[kx] += c * v.x - s * v.y;
      gi[kx] += c * v.y + s * v.x;
    }
  }
  float2* gp = g + (plane * 256 + y) * 16;
  const float sc = 1.0f / 65536.0f;
#pragma unroll
  for (int kx = 0; kx < 16; ++kx) {
    float m = (kx == 0) ? sc : 2.0f * sc;
    gp[kx] = make_float2(gr[kx] * m, gi[kx] * m);
  }
}

// ---------- K_LAYER: hout = GELU( invDFT_x(g) + conv1x1(h, ww) + wb ) ----------
__global__ __launch_bounds__(256) void k_layer(const float* __restrict__ h, const float2* __restrict__ g,
                                               const float* __restrict__ ww, const float* __restrict__ wb,
                                               const float* __restrict__ cosT, const float* __restrict__ sinT,
                                               float* __restrict__ hout) {
  int bid = blockIdx.x;                 // 1024 = B*H
  int b = bid >> 8, y = bid & 255;
  int tid = threadIdx.x;
  int to = tid >> 5, tx = tid & 31;
  int o0 = to * 8, x0 = tx * 8;
  __shared__ float hs[16 * 256];
  __shared__ float wsT[64 * 68];        // wsT[c][o], padded stride 68
  __shared__ float gsf[64 * 32];        // [o][kx*2 + reim]
#pragma unroll 1
  for (int rep = 0; rep < 16; ++rep) {
    int flat = rep * 256 + tid;
    wsT[(flat & 63) * 68 + (flat >> 6)] = ww[flat];
  }
#pragma unroll 1
  for (int rep = 0; rep < 8; ++rep) {
    int flat = rep * 256 + tid;
    int o = flat >> 5, i = flat & 31;
    gsf[flat] = ((const float*)g)[((b * 64 + o) * 256 + y) * 32 + i];
  }
  float acc[8][8];
#pragma unroll
  for (int i = 0; i < 8; ++i)
#pragma unroll
    for (int j = 0; j < 8; ++j) acc[i][j] = 0.f;

  for (int ch = 0; ch < 4; ++ch) {
    __syncthreads();
#pragma unroll 1
    for (int rep = 0; rep < 16; ++rep) {
      int flat = rep * 256 + tid;
      hs[flat] = h[((b * 64 + ch * 16 + (flat >> 8)) * 256 + y) * 256 + (flat & 255)];
    }
    __syncthreads();
#pragma unroll
    for (int cc = 0; cc < 16; ++cc) {
      int c = ch * 16 + cc;
      float4 wA = *(const float4*)&wsT[c * 68 + o0];
      float4 wB = *(const float4*)&wsT[c * 68 + o0 + 4];
      float4 hA = *(const float4*)&hs[cc * 256 + x0];
      float4 hB = *(const float4*)&hs[cc * 256 + x0 + 4];
      float wv[8] = {wA.x, wA.y, wA.z, wA.w, wB.x, wB.y, wB.z, wB.w};
      float hv[8] = {hA.x, hA.y, hA.z, hA.w, hB.x, hB.y, hB.z, hB.w};
#pragma unroll
      for (int i = 0; i < 8; ++i)
#pragma unroll
        for (int j = 0; j < 8; ++j) acc[i][j] += wv[i] * hv[j];
    }
  }
  // spectral inverse over x: acc += gr*cos - gi*sin
  const float4* ct4 = (const float4*)cosT;
  const float4* st4 = (const float4*)sinT;
#pragma unroll 1
  for (int kx = 0; kx < 16; ++kx) {
    float4 cA = ct4[kx * 64 + tx * 2], cB = ct4[kx * 64 + tx * 2 + 1];
    float4 sA = st4[kx * 64 + tx * 2], sB = st4[kx * 64 + tx * 2 + 1];
    float tc[8] = {cA.x, cA.y, cA.z, cA.w, cB.x, cB.y, cB.z, cB.w};
    float tsv[8] = {sA.x, sA.y, sA.z, sA.w, sB.x, sB.y, sB.z, sB.w};
#pragma unroll
    for (int i = 0; i < 8; ++i) {
      float grv = gsf[(o0 + i) * 32 + kx * 2];
      float giv = gsf[(o0 + i) * 32 + kx * 2 + 1];
#pragma unroll
      for (int j = 0; j < 8; ++j) acc[i][j] += grv * tc[j] - giv * tsv[j];
    }
  }
#pragma unroll 1
  for (int i = 0; i < 8; ++i) {
    int o = o0 + i;
    float bia = wb[o];
    float r[8];
#pragma unroll
    for (int j = 0; j < 8; ++j) {
      float v = acc[i][j] + bia;
      r[j] = 0.5f * v * (1.0f + erff(v * 0.70710678118654752f));
    }
    float* op = &hout[((b * 64 + o) * 256 + y) * 256 + x0];
    *(float4*)op = make_float4(r[0], r[1], r[2], r[3]);
    *(float4*)(op + 4) = make_float4(r[4], r[5], r[6], r[7]);
  }
}

// ---------- K_FINAL: out = fc2( GELU( fc1(h) ) ) ----------
__global__ __launch_bounds__(256) void k_final(const float* __restrict__ h, const float* __restrict__ w1,
                                               const float* __restrict__ b1, const float* __restrict__ w2,
                                               const float* __restrict__ b2, float* __restrict__ out) {
  int bid = blockIdx.x;                 // 2048 = B * H * 2
  int xh = bid & 1, y = (bid >> 1) & 255, b = bid >> 9;
  int tid = threadIdx.x;
  int tj = tid >> 4, txi = tid & 15;
  int j0 = tj * 8;
  __shared__ float w1T[64 * 132];       // [c][j] padded
  __shared__ float hs[16 * 128];
  __shared__ float red[16 * 16 * 9];
#pragma unroll 1
  for (int rep = 0; rep < 32; ++rep) {
    int flat = rep * 256 + tid;
    w1T[(flat & 63) * 132 + (flat >> 6)] = w1[flat];
  }
  float acc[8][8];
#pragma unroll
  for (int i = 0; i < 8; ++i)
#pragma unroll
    for (int j = 0; j < 8; ++j) acc[i][j] = 0.f;

  for (int ch = 0; ch < 4; ++ch) {
    __syncthreads();
#pragma unroll 1
    for (int rep = 0; rep < 8; ++rep) {
      int flat = rep * 256 + tid;
      hs[flat] = h[((b * 64 + ch * 16 + (flat >> 7)) * 256 + y) * 256 + xh * 128 + (flat & 127)];
    }
    __syncthreads();
#pragma unroll
    for (int cc = 0; cc < 16; ++cc) {
      int c = ch * 16 + cc;
      float4 wA = *(const float4*)&w1T[c * 132 + j0];
      float4 wB = *(const float4*)&w1T[c * 132 + j0 + 4];
      float4 hA = *(const float4*)&hs[cc * 128 + txi * 8];
      float4 hB = *(const float4*)&hs[cc * 128 + txi * 8 + 4];
      float wv[8] = {wA.x, wA.y, wA.z, wA.w, wB.x, wB.y, wB.z, wB.w};
      float hv[8] = {hA.x, hA.y, hA.z, hA.w, hB.x, hB.y, hB.z, hB.w};
#pragma unroll
      for (int i = 0; i < 8; ++i)
#pragma unroll
        for (int j = 0; j < 8; ++j) acc[i][j] += wv[i] * hv[j];
    }
  }
  float p[8];
#pragma unroll
  for (int q = 0; q < 8; ++q) p[q] = 0.f;
#pragma unroll 1
  for (int i = 0; i < 8; ++i) {
    int j = j0 + i;
    float bia = b1[j], f2 = w2[j];
#pragma unroll
    for (int q = 0; q < 8; ++q) {
      float v = acc[i][q] + bia;
      float a = 0.5f * v * (1.0f + erff(v * 0.70710678118654752f));
      p[q] += f2 * a;
    }
  }
#pragma unroll
  for (int q = 0; q < 8; ++q) red[tid * 9 + q] = p[q];
  __syncthreads();
  if (tid < 128) {
    int txx = tid >> 3, xi = tid & 7;
    float s = 0.f;
#pragma unroll
    for (int t = 0; t < 16; ++t) s += red[(t * 16 + txx) * 9 + xi];
    out[(b * 256 + y) * 256 + xh * 128 + txx * 8 + xi] = s + b2[0];
  }
}

extern "C" void kernel_launch(void* const* d_in, const int* in_sizes, int n_in,
                              void* d_out, int out_size, void* d_ws, size_t ws_size,
                              hipStream_t stream) {
  const float* x       = (const float*)d_in[0];
  const float* fc0_w   = (const float*)d_in[1];
  const float* fc0_b   = (const float*)d_in[2];
  const float* spec_wr = (const float*)d_in[3];
  const float* spec_wi = (const float*)d_in[4];
  const float* w_w     = (const float*)d_in[5];
  const float* w_b     = (const float*)d_in[6];
  const float* fc1_w   = (const float*)d_in[7];
  const float* fc1_b   = (const float*)d_in[8];
  const float* fc2_w   = (const float*)d_in[9];
  const float* fc2_b   = (const float*)d_in[10];
  float* out = (float*)d_out;

  char* ws = (char*)d_ws;
  float*  h0   = (float*)ws;                               // 67108864 B
  float*  h1   = (float*)(ws + 67108864);                  // 67108864 B
  float2* A    = (float2*)(ws + 134217728);                // 33554432 B
  float2* g    = (float2*)(ws + 167772160);                // 33554432 B
  float2* X    = (float2*)(ws + 201326592);                // 524288 B
  float2* Y    = (float2*)(ws + 201850880);                // 524288 B
  float*  cosT = (float*)(ws + 202375168);                 // 16384 B
  float*  sinT = cosT + 4096;                              // 16384 B

  k_tables<<<16, 256, 0, stream>>>(cosT, sinT);
  k_fc0<<<1024, 256, 0, stream>>>(x, fc0_w, fc0_b, h0);
  float* hc = h0; float* hn = h1;
  for (int l = 0; l < 4; ++l) {
    k_f1<<<4096, 256, 0, stream>>>(hc, (const float4*)cosT, (const float4*)sinT, A);
    k_f2<<<256, 256, 0, stream>>>(A, cosT, sinT, X);
    k_mix<<<256, 256, 0, stream>>>(X, spec_wr + (size_t)l * 1048576, spec_wi + (size_t)l * 1048576, Y);
    k_inv1<<<256, 256, 0, stream>>>(Y, cosT, sinT, g);
    k_layer<<<1024, 256, 0, stream>>>(hc, g, w_w + l * 4096, w_b + l * 64, cosT, sinT, hn);
    float* t = hc; hc = hn; hn = t;
  }
  k_final<<<2048, 256, 0, stream>>>(hc, fc1_w, fc1_b, fc2_w, fc2_b, out);
}

// Round 2
// 1170.081 us; speedup vs baseline: 1.7341x; 1.7341x over previous
//
#include <hip/hip_runtime.h>
#include <math.h>

#define HW 65536

// ---------- tables: cosT/sinT[k][x] (16x256) and ET[j][x] (32x256, j=2k:cos, j=2k+1:-sin) ----------
__global__ __launch_bounds__(256) void k_tables(float* __restrict__ cosT, float* __restrict__ sinT,
                                                float* __restrict__ ET) {
  int idx = blockIdx.x * 256 + threadIdx.x;   // 48*256 = 12288 >= 4096 + 8192
  const float w = 0.0245436926061702596f;     // 2*pi/256
  if (idx < 4096) {
    int k = idx >> 8, xx = idx & 255;
    int t = (k * xx) & 255;
    float ang = (float)t * w;
    cosT[idx] = cosf(ang);
    sinT[idx] = sinf(ang);
  } else if (idx < 12288) {
    int e = idx - 4096;
    int j = e >> 8, xx = e & 255;
    int k = j >> 1;
    int t = (k * xx) & 255;
    float ang = (float)t * w;
    ET[e] = (j & 1) ? -sinf(ang) : cosf(ang);
  }
}

// ---------- fc0: (B,3,H,W) -> (B,64,H,W) ----------
__global__ __launch_bounds__(256) void k_fc0(const float* __restrict__ x, const float* __restrict__ w,
                                             const float* __restrict__ b, float* __restrict__ h) {
  int bid = blockIdx.x;                 // 1024 = B*H
  int bb = bid >> 8, y = bid & 255;
  int tx = threadIdx.x;
  __shared__ float ws[192];
  __shared__ float bs[64];
  if (tx < 192) ws[tx] = w[tx];
  if (tx < 64) bs[tx] = b[tx];
  __syncthreads();
  const float* xp = x + ((bb * 3) * 256 + y) * 256 + tx;
  float v0 = xp[0], v1 = xp[HW], v2 = xp[2 * HW];
  float* hp = h + ((bb * 64) * 256 + y) * 256 + tx;
#pragma unroll 4
  for (int o = 0; o < 64; ++o) {
    hp[o * HW] = bs[o] + ws[o * 3] * v0 + ws[o * 3 + 1] * v1 + ws[o * 3 + 2] * v2;
  }
}

// ---------- F1 as register-tiled GEMM: A[r][k] (float2), r = (b*64+c)*256+y ----------
// Block: 256 rows, 256 threads (tn 0..7 x tm 0..31), thread tile 8 rows x 4 cols.
__global__ __launch_bounds__(256) void k_f1(const float* __restrict__ h, const float* __restrict__ ET,
                                            float2* __restrict__ A) {
  __shared__ float es[32 * 260];   // E^T padded
  __shared__ float hs[256 * 36];   // 256 rows x 32 k-chunk, padded stride 36
  int tid = threadIdx.x;
  int tm = tid & 31, tn = tid >> 5;
  int r0 = blockIdx.x * 256;
  int base = r0 * 256;
#pragma unroll
  for (int rep = 0; rep < 32; ++rep) {
    int flat = rep * 256 + tid;
    es[(flat >> 8) * 260 + (flat & 255)] = ET[flat];
  }
  float4 st[8];
  {
    const float4* hp = (const float4*)(h + base);
#pragma unroll
    for (int q = 0; q < 8; ++q) {
      int flat = q * 256 + tid;
      st[q] = hp[(flat >> 3) * 64 + (flat & 7)];
    }
  }
  float acc[8][4];
#pragma unroll
  for (int i = 0; i < 8; ++i)
#pragma unroll
    for (int p = 0; p < 4; ++p) acc[i][p] = 0.f;

  for (int xc = 0; xc < 8; ++xc) {
    __syncthreads();
#pragma unroll
    for (int q = 0; q < 8; ++q) {
      int flat = q * 256 + tid;
      *(float4*)&hs[(flat >> 3) * 36 + (flat & 7) * 4] = st[q];
    }
    __syncthreads();
    if (xc < 7) {
      const float4* hp = (const float4*)(h + base) + (xc + 1) * 8;
#pragma unroll
      for (int q = 0; q < 8; ++q) {
        int flat = q * 256 + tid;
        st[q] = hp[(flat >> 3) * 64 + (flat & 7)];
      }
    }
    int xbase = xc * 32;
#pragma unroll
    for (int kk = 0; kk < 32; kk += 4) {
      float4 e0 = *(const float4*)&es[(tn * 4 + 0) * 260 + xbase + kk];
      float4 e1 = *(const float4*)&es[(tn * 4 + 1) * 260 + xbase + kk];
      float4 e2 = *(const float4*)&es[(tn * 4 + 2) * 260 + xbase + kk];
      float4 e3 = *(const float4*)&es[(tn * 4 + 3) * 260 + xbase + kk];
#pragma unroll
      for (int i = 0; i < 8; ++i) {
        float4 hv = *(const float4*)&hs[(tm + 32 * i) * 36 + kk];
        acc[i][0] += hv.x * e0.x + hv.y * e0.y + hv.z * e0.z + hv.w * e0.w;
        acc[i][1] += hv.x * e1.x + hv.y * e1.y + hv.z * e1.z + hv.w * e1.w;
        acc[i][2] += hv.x * e2.x + hv.y * e2.y + hv.z * e2.z + hv.w * e2.w;
        acc[i][3] += hv.x * e3.x + hv.y * e3.y + hv.z * e3.z + hv.w * e3.w;
      }
    }
  }
#pragma unroll
  for (int i = 0; i < 8; ++i) {
    int r = r0 + tm + 32 * i;
    *(float4*)&A[r * 16 + tn * 2] = make_float4(acc[i][0], acc[i][1], acc[i][2], acc[i][3]);
  }
}

// ---------- F2: col DFT over y, LDS-staged ----------
__global__ __launch_bounds__(256) void k_f2(const float2* __restrict__ A, const float* __restrict__ cosT,
                                            const float* __restrict__ sinT, float2* __restrict__ X) {
  int plane = blockIdx.x;               // 256 = B*C
  int tid = threadIdx.x;
  __shared__ float2 As[256 * 16];       // 32 KB
  __shared__ float ct[16 * 257];
  __shared__ float stt[16 * 257];
  const float2* Ap = A + plane * 4096;
#pragma unroll
  for (int rep = 0; rep < 16; ++rep) {
    int flat = rep * 256 + tid;
    As[flat] = Ap[flat];
  }
#pragma unroll
  for (int rep = 0; rep < 16; ++rep) {
    int flat = rep * 256 + tid;
    int ky = flat >> 8, y = flat & 255;
    ct[ky * 257 + y] = cosT[flat];
    stt[ky * 257 + y] = sinT[flat];
  }
  __syncthreads();
  int ky = tid >> 4, kx = tid & 15;
  float xr = 0.f, xi = 0.f;
#pragma unroll 4
  for (int y = 0; y < 256; ++y) {
    float2 a = As[y * 16 + kx];
    float c = ct[ky * 257 + y], s = stt[ky * 257 + y];
    xr += c * a.x + s * a.y;
    xi += c * a.y - s * a.x;
  }
  X[plane * 256 + tid] = make_float2(xr, xi);
}

// ---------- MIX: Y[b,o,m] = sum_c X[b,c,m] * (wr+i wi)[c,o,m], c split 4-way in-block ----------
__global__ __launch_bounds__(256) void k_mix(const float2* __restrict__ X, const float* __restrict__ wr,
                                             const float* __restrict__ wi, float2* __restrict__ Y) {
  int o = blockIdx.x >> 2;              // 64 o * 4 m-chunks
  int mc = blockIdx.x & 3;
  int tid = threadIdx.x;
  int cg = tid >> 6, m2 = tid & 63;
  int m = mc * 64 + m2;
  float yr[4] = {0.f, 0.f, 0.f, 0.f}, yi[4] = {0.f, 0.f, 0.f, 0.f};
#pragma unroll 4
  for (int cc = 0; cc < 16; ++cc) {
    int c = cg * 16 + cc;
    float r = wr[(c * 64 + o) * 256 + m];
    float im = wi[(c * 64 + o) * 256 + m];
#pragma unroll
    for (int b = 0; b < 4; ++b) {
      float2 xv = X[(b * 64 + c) * 256 + m];
      yr[b] += xv.x * r - xv.y * im;
      yi[b] += xv.x * im + xv.y * r;
    }
  }
  __shared__ float2 red[1024];
#pragma unroll
  for (int b = 0; b < 4; ++b) red[cg * 256 + b * 64 + m2] = make_float2(yr[b], yi[b]);
  __syncthreads();
  int b = tid >> 6;
  float sx = 0.f, sy = 0.f;
#pragma unroll
  for (int g2 = 0; g2 < 4; ++g2) {
    float2 v = red[g2 * 256 + b * 64 + m2];
    sx += v.x; sy += v.y;
  }
  Y[(b * 64 + o) * 256 + m] = make_float2(sx, sy);
}

// ---------- INV1: g[b,o,y,kx] = sum_ky Y[b,o,ky,kx] e^{+2pi i ky y/256}, scaled ----------
__global__ __launch_bounds__(256) void k_inv1(const float2* __restrict__ Y, const float* __restrict__ cosT,
                                              const float* __restrict__ sinT, float2* __restrict__ g) {
  int plane = blockIdx.x;               // 256 = B*O
  int y = threadIdx.x;
  __shared__ float2 Ys[256];
  Ys[threadIdx.x] = Y[plane * 256 + threadIdx.x];
  __syncthreads();
  float gr[16], gi[16];
#pragma unroll
  for (int k = 0; k < 16; ++k) { gr[k] = 0.f; gi[k] = 0.f; }
  for (int ky = 0; ky < 16; ++ky) {
    float c = cosT[ky * 256 + y], s = sinT[ky * 256 + y];
#pragma unroll
    for (int kx = 0; kx < 16; ++kx) {
      float2 v = Ys[ky * 16 + kx];
      gr[kx] += c * v.x - s * v.y;
      gi[kx] += c * v.y + s * v.x;
    }
  }
  float2* gp = g + (plane * 256 + y) * 16;
  const float sc = 1.0f / 65536.0f;
#pragma unroll
  for (int kx = 0; kx < 16; ++kx) {
    float m = (kx == 0) ? sc : 2.0f * sc;
    gp[kx] = make_float2(gr[kx] * m, gi[kx] * m);
  }
}

// ---------- K_LAYER: hout = GELU( invDFT_x(g) + conv1x1(h, ww) + wb ) ----------
__global__ __launch_bounds__(256) void k_layer(const float* __restrict__ h, const float2* __restrict__ g,
                                               const float* __restrict__ ww, const float* __restrict__ wb,
                                               const float* __restrict__ cosT, const float* __restrict__ sinT,
                                               float* __restrict__ hout) {
  int bid = blockIdx.x;                 // 1024 = B*H
  int b = bid >> 8, y = bid & 255;
  int tid = threadIdx.x;
  int to = tid >> 5, tx = tid & 31;
  int o0 = to * 8, x0 = tx * 8;
  __shared__ float hs[16 * 256];
  __shared__ float wsT[64 * 68];        // wsT[c][o], padded stride 68
  __shared__ float gsf2[32 * 68];       // [ikx][o], padded stride 68
#pragma unroll 1
  for (int rep = 0; rep < 16; ++rep) {
    int flat = rep * 256 + tid;
    wsT[(flat & 63) * 68 + (flat >> 6)] = ww[flat];
  }
#pragma unroll 1
  for (int rep = 0; rep < 8; ++rep) {
    int flat = rep * 256 + tid;
    int o = flat >> 5, ikx = flat & 31;
    gsf2[ikx * 68 + o] = ((const float*)g)[((b * 64 + o) * 256 + y) * 32 + ikx];
  }
  float acc[8][8];
#pragma unroll
  for (int i = 0; i < 8; ++i)
#pragma unroll
    for (int j = 0; j < 8; ++j) acc[i][j] = 0.f;

  for (int ch = 0; ch < 4; ++ch) {
    __syncthreads();
#pragma unroll 1
    for (int rep = 0; rep < 16; ++rep) {
      int flat = rep * 256 + tid;
      hs[flat] = h[((b * 64 + ch * 16 + (flat >> 8)) * 256 + y) * 256 + (flat & 255)];
    }
    __syncthreads();
#pragma unroll
    for (int cc = 0; cc < 16; ++cc) {
      int c = ch * 16 + cc;
      float4 wA = *(const float4*)&wsT[c * 68 + o0];
      float4 wB = *(const float4*)&wsT[c * 68 + o0 + 4];
      float4 hA = *(const float4*)&hs[cc * 256 + x0];
      float4 hB = *(const float4*)&hs[cc * 256 + x0 + 4];
      float wv[8] = {wA.x, wA.y, wA.z, wA.w, wB.x, wB.y, wB.z, wB.w};
      float hv[8] = {hA.x, hA.y, hA.z, hA.w, hB.x, hB.y, hB.z, hB.w};
#pragma unroll
      for (int i = 0; i < 8; ++i)
#pragma unroll
        for (int j = 0; j < 8; ++j) acc[i][j] += wv[i] * hv[j];
    }
  }
  // spectral inverse over x: acc += gr*cos - gi*sin
  const float4* ct4 = (const float4*)cosT;
  const float4* st4 = (const float4*)sinT;
#pragma unroll 1
  for (int kx = 0; kx < 16; ++kx) {
    float4 cA = ct4[kx * 64 + tx * 2], cB = ct4[kx * 64 + tx * 2 + 1];
    float4 sA = st4[kx * 64 + tx * 2], sB = st4[kx * 64 + tx * 2 + 1];
    float tc[8] = {cA.x, cA.y, cA.z, cA.w, cB.x, cB.y, cB.z, cB.w};
    float tsv[8] = {sA.x, sA.y, sA.z, sA.w, sB.x, sB.y, sB.z, sB.w};
    float4 grA = *(const float4*)&gsf2[(kx * 2) * 68 + o0];
    float4 grB = *(const float4*)&gsf2[(kx * 2) * 68 + o0 + 4];
    float4 giA = *(const float4*)&gsf2[(kx * 2 + 1) * 68 + o0];
    float4 giB = *(const float4*)&gsf2[(kx * 2 + 1) * 68 + o0 + 4];
    float gr[8] = {grA.x, grA.y, grA.z, grA.w, grB.x, grB.y, grB.z, grB.w};
    float gi[8] = {giA.x, giA.y, giA.z, giA.w, giB.x, giB.y, giB.z, giB.w};
#pragma unroll
    for (int i = 0; i < 8; ++i)
#pragma unroll
      for (int j = 0; j < 8; ++j) acc[i][j] += gr[i] * tc[j] - gi[i] * tsv[j];
  }
#pragma unroll 1
  for (int i = 0; i < 8; ++i) {
    int o = o0 + i;
    float bia = wb[o];
    float r[8];
#pragma unroll
    for (int j = 0; j < 8; ++j) {
      float v = acc[i][j] + bia;
      r[j] = 0.5f * v * (1.0f + erff(v * 0.70710678118654752f));
    }
    float* op = &hout[((b * 64 + o) * 256 + y) * 256 + x0];
    *(float4*)op = make_float4(r[0], r[1], r[2], r[3]);
    *(float4*)(op + 4) = make_float4(r[4], r[5], r[6], r[7]);
  }
}

// ---------- K_FINAL: out = fc2( GELU( fc1(h) ) ) ----------
__global__ __launch_bounds__(256) void k_final(const float* __restrict__ h, const float* __restrict__ w1,
                                               const float* __restrict__ b1, const float* __restrict__ w2,
                                               const float* __restrict__ b2, float* __restrict__ out) {
  int bid = blockIdx.x;                 // 2048 = B * H * 2
  int xh = bid & 1, y = (bid >> 1) & 255, b = bid >> 9;
  int tid = threadIdx.x;
  int tj = tid >> 4, txi = tid & 15;
  int j0 = tj * 8;
  __shared__ float w1T[64 * 132];       // [c][j] padded
  __shared__ float hs[16 * 128];
  __shared__ float red[16 * 16 * 9];
#pragma unroll 1
  for (int rep = 0; rep < 32; ++rep) {
    int flat = rep * 256 + tid;
    w1T[(flat & 63) * 132 + (flat >> 6)] = w1[flat];
  }
  float acc[8][8];
#pragma unroll
  for (int i = 0; i < 8; ++i)
#pragma unroll
    for (int j = 0; j < 8; ++j) acc[i][j] = 0.f;

  for (int ch = 0; ch < 4; ++ch) {
    __syncthreads();
#pragma unroll 1
    for (int rep = 0; rep < 8; ++rep) {
      int flat = rep * 256 + tid;
      hs[flat] = h[((b * 64 + ch * 16 + (flat >> 7)) * 256 + y) * 256 + xh * 128 + (flat & 127)];
    }
    __syncthreads();
#pragma unroll
    for (int cc = 0; cc < 16; ++cc) {
      int c = ch * 16 + cc;
      float4 wA = *(const float4*)&w1T[c * 132 + j0];
      float4 wB = *(const float4*)&w1T[c * 132 + j0 + 4];
      float4 hA = *(const float4*)&hs[cc * 128 + txi * 8];
      float4 hB = *(const float4*)&hs[cc * 128 + txi * 8 + 4];
      float wv[8] = {wA.x, wA.y, wA.z, wA.w, wB.x, wB.y, wB.z, wB.w};
      float hv[8] = {hA.x, hA.y, hA.z, hA.w, hB.x, hB.y, hB.z, hB.w};
#pragma unroll
      for (int i = 0; i < 8; ++i)
#pragma unroll
        for (int j = 0; j < 8; ++j) acc[i][j] += wv[i] * hv[j];
    }
  }
  float p[8];
#pragma unroll
  for (int q = 0; q < 8; ++q) p[q] = 0.f;
#pragma unroll 1
  for (int i = 0; i < 8; ++i) {
    int j = j0 + i;
    float bia = b1[j], f2 = w2[j];
#pragma unroll
    for (int q = 0; q < 8; ++q) {
      float v = acc[i][q] + bia;
      float a = 0.5f * v * (1.0f + erff(v * 0.70710678118654752f));
      p[q] += f2 * a;
    }
  }
#pragma unroll
  for (int q = 0; q < 8; ++q) red[tid * 9 + q] = p[q];
  __syncthreads();
  if (tid < 128) {
    int txx = tid >> 3, xi = tid & 7;
    float s = 0.f;
#pragma unroll
    for (int t = 0; t < 16; ++t) s += red[(t * 16 + txx) * 9 + xi];
    out[(b * 256 + y) * 256 + xh * 128 + txx * 8 + xi] = s + b2[0];
  }
}

extern "C" void kernel_launch(void* const* d_in, const int* in_sizes, int n_in,
                              void* d_out, int out_size, void* d_ws, size_t ws_size,
                              hipStream_t stream) {
  const float* x       = (const float*)d_in[0];
  const float* fc0_w   = (const float*)d_in[1];
  const float* fc0_b   = (const float*)d_in[2];
  const float* spec_wr = (const float*)d_in[3];
  const float* spec_wi = (const float*)d_in[4];
  const float* w_w     = (const float*)d_in[5];
  const float* w_b     = (const float*)d_in[6];
  const float* fc1_w   = (const float*)d_in[7];
  const float* fc1_b   = (const float*)d_in[8];
  const float* fc2_w   = (const float*)d_in[9];
  const float* fc2_b   = (const float*)d_in[10];
  float* out = (float*)d_out;

  char* ws = (char*)d_ws;
  float*  h0   = (float*)ws;                               // 67108864 B
  float*  h1   = (float*)(ws + 67108864);                  // 67108864 B
  float2* A    = (float2*)(ws + 134217728);                // 8388608 B
  float2* g    = (float2*)(ws + 142606336);                // 8388608 B
  float2* X    = (float2*)(ws + 150994944);                // 524288 B
  float2* Y    = (float2*)(ws + 151519232);                // 524288 B
  float*  cosT = (float*)(ws + 152043520);                 // 16384 B
  float*  sinT = cosT + 4096;                              // 16384 B
  float*  ET   = sinT + 4096;                              // 32768 B

  k_tables<<<48, 256, 0, stream>>>(cosT, sinT, ET);
  k_fc0<<<1024, 256, 0, stream>>>(x, fc0_w, fc0_b, h0);
  float* hc = h0; float* hn = h1;
  for (int l = 0; l < 4; ++l) {
    k_f1<<<256, 256, 0, stream>>>(hc, ET, A);
    k_f2<<<256, 256, 0, stream>>>(A, cosT, sinT, X);
    k_mix<<<256, 256, 0, stream>>>(X, spec_wr + (size_t)l * 1048576, spec_wi + (size_t)l * 1048576, Y);
    k_inv1<<<256, 256, 0, stream>>>(Y, cosT, sinT, g);
    k_layer<<<1024, 256, 0, stream>>>(hc, g, w_w + l * 4096, w_b + l * 64, cosT, sinT, hn);
    float* t = hc; hc = hn; hn = t;
  }
  k_final<<<2048, 256, 0, stream>>>(hc, fc1_w, fc1_b, fc2_w, fc2_b, out);
}